// Round 3
// baseline (715.665 us; speedup 1.0000x reference)
//
#include <hip/hip_runtime.h>

#define NN 50000
#define NE 800000
#define DD 128
#define PEW 98
#define KPE 226
#define WSLOT 32768   // bf16 elements per weight slot (128 n x 256 k)
#define NB 49         // scan blocks per level: ceil(NN/1024)
#define GX 782        // ceil(NN/64) gemm row-tiles
#define HISTB 782     // ceil(NE/(256*4)) hist blocks per level (4 edges/thread)
#define FILLB 782     // ceil(NE/(256*4)) fill blocks per level
#define PREPXB 6250   // NN*256/(256*8) prepx blocks (8 elems/thread)
#define PREPB 48      // 6 slots x 8 tile-blocks
#define AGG2B 25000   // blocks per level: 2 nodes/block, 2 waves/node

typedef __attribute__((ext_vector_type(8))) short short8;
typedef __attribute__((ext_vector_type(4))) float float4v;
typedef __attribute__((ext_vector_type(4))) int int4v;   // clang vector: OK for nontemporal builtins

// Kept so anything that looks up the original kernel name still finds a symbol.
__global__ void GraphTrajSTEncoder_67362267070834_kernel() {}

// ---------------- dtype helpers ----------------

__device__ __forceinline__ float bfbits_to_f(unsigned int u16) {
    unsigned int v = u16 << 16;
    float f;
    __builtin_memcpy(&f, &v, 4);
    return f;
}

__device__ __forceinline__ float bits_to_f(unsigned int v) {
    float f;
    __builtin_memcpy(&f, &v, 4);
    return f;
}

__device__ __forceinline__ int f_as_i(float f) {
    int i;
    __builtin_memcpy(&i, &f, 4);
    return i;
}

__device__ __forceinline__ unsigned short f_to_bfbits(float f) {
    unsigned int b;
    __builtin_memcpy(&b, &f, 4);
    unsigned int r = b + 0x7FFFu + ((b >> 16) & 1u);   // round to nearest even
    return (unsigned short)(r >> 16);
}

__device__ __forceinline__ float ldf(const void* p, int i, int isbf) {
    if (isbf) return bfbits_to_f(((const unsigned short*)p)[i]);
    return ((const float*)p)[i];
}

// ---------------- dispatch 1: dtype detect + zero degree arrays ----------------
__global__ __launch_bounds__(256)
void k_detect0(const unsigned int* xw, int* flag, float* dout_sentinel,
               int* deg0, int* deg1) {
    if (blockIdx.x == 0) {
        __shared__ int cnt;
        if (threadIdx.x == 0) cnt = 0;
        __syncthreads();
        unsigned int w = xw[threadIdx.x];
        unsigned int e = (w >> 7) & 0xFFu;
        atomicAdd(&cnt, (e >= 100u && e <= 150u) ? 1 : 0);
        __syncthreads();
        if (threadIdx.x == 0) {
            flag[0] = (cnt >= 128) ? 1 : 0;
            dout_sentinel[0] = 1.0e6f;
        }
    } else {
        int i = (blockIdx.x - 1) * 256 + threadIdx.x;
        if (i < NN) deg0[i] = 0;
        else if (i < 2 * NN) deg1[i - NN] = 0;
    }
}

// ---------------- dispatch 2 (kA): hist(+rank) + prepx + weight-prep -------
// hist: 4 edges/thread, atomicAdd returns per-edge rank within node -> rank_buf
// prepx: 8 elems/thread, vectorized
// slot y (0..5), Wt[n*256 + k]:
//   y<2 : nodeLin y   -> src[k*128+n], k<226, else 0
//   y>=2: layer y-2   -> k<128: lin1[k*128+n]; k>=128: lin2[(k-128)*128+n]
__global__ __launch_bounds__(256)
void kA(const int* __restrict__ ei0, const int* __restrict__ ei1,
        int* deg0, int* deg1,
        int* __restrict__ rank0, int* __restrict__ rank1,
        const void* x, const void* pe, unsigned short* __restrict__ xcat,
        const void* n1, const void* n2,
        const void* l11, const void* l21, const void* l12, const void* l22,
        const void* l13, const void* l23, const void* l14, const void* l24,
        unsigned short* __restrict__ wt, const int* __restrict__ dflag) {
    int b = blockIdx.x;
    int t = threadIdx.x;
    if (b < 2 * HISTB) {
        int lvl = b >= HISTB;
        const int* col = (lvl ? ei1 : ei0) + NE;
        int* deg = lvl ? deg1 : deg0;
        int* rank = lvl ? rank1 : rank0;
        int i0 = ((b - (lvl ? HISTB : 0)) * 256 + t) * 4;
        if (i0 < NE) {   // NE % 4 == 0 -> full quads only
            int4 c = *(const int4*)(col + i0);
            int4 r;
            r.x = atomicAdd(&deg[c.x], 1);
            r.y = atomicAdd(&deg[c.y], 1);
            r.z = atomicAdd(&deg[c.z], 1);
            r.w = atomicAdd(&deg[c.w], 1);
            *(int4*)(rank + i0) = r;
        }
    } else if (b < 2 * HISTB + PREPXB) {
        int isbf = dflag[0];
        int id0 = (b - 2 * HISTB) * 2048 + t * 8;
        int row = id0 >> 8, c0 = id0 & 255;   // c0 is a multiple of 8
        union { unsigned short u[8]; short8 v; } ob;
        if (c0 < DD) {
            // 8 consecutive x columns
            if (isbf) {
                ob.v = *(const short8*)((const unsigned short*)x + row * DD + c0);
            } else {
                float f[8];
                __builtin_memcpy(f, (const float*)x + row * DD + c0, 32);
#pragma unroll
                for (int j = 0; j < 8; j++) ob.u[j] = f_to_bfbits(f[j]);
            }
        } else if (c0 + 8 <= KPE) {
            // 8 consecutive pe columns (c0 = 128..216)
            int off = row * PEW + (c0 - DD);
            if (isbf) {
                unsigned short tmp[8];
                __builtin_memcpy(tmp, (const unsigned short*)pe + off, 16);
#pragma unroll
                for (int j = 0; j < 8; j++) ob.u[j] = tmp[j];
            } else {
                float f[8];
                __builtin_memcpy(f, (const float*)pe + off, 32);
#pragma unroll
                for (int j = 0; j < 8; j++) ob.u[j] = f_to_bfbits(f[j]);
            }
        } else {
            // mixed tail (c0 = 224) or pure zero pad (c0 = 232/240/248)
#pragma unroll
            for (int j = 0; j < 8; j++) {
                int c = c0 + j;
                float v = 0.f;
                if (c < KPE) v = ldf(pe, row * PEW + (c - DD), isbf);
                ob.u[j] = f_to_bfbits(v);
            }
        }
        *(short8*)(xcat + id0) = ob.v;
    } else {
        int b3 = b - 2 * HISTB - PREPXB;
        int y = b3 >> 3, bx = b3 & 7;
        int kt = bx >> 1, nt = bx & 1;
        __shared__ float tile[64][65];
        int cc = t & 63, rr = t >> 6;
        int k0 = kt * 64, n0 = nt * 64;
        int isbf = dflag[0];
        const void* sA;   // source for k<128
        const void* sB;   // source for k>=128
        if (y == 0)      { sA = n1;  sB = n1; }
        else if (y == 1) { sA = n2;  sB = n2; }
        else if (y == 2) { sA = l11; sB = l21; }
        else if (y == 3) { sA = l12; sB = l22; }
        else if (y == 4) { sA = l13; sB = l23; }
        else             { sA = l14; sB = l24; }
#pragma unroll
        for (int i = 0; i < 16; i++) {
            int k = k0 + rr + i * 4;
            float v = 0.f;
            if (y < 2) {
                if (k < KPE) v = ldf(sA, k * DD + n0 + cc, isbf);
            } else {
                v = (k < 128) ? ldf(sA, k * DD + n0 + cc, isbf)
                              : ldf(sB, (k - 128) * DD + n0 + cc, isbf);
            }
            tile[rr + i * 4][cc] = v;
        }
        __syncthreads();
        unsigned short* w = wt + y * WSLOT;
#pragma unroll
        for (int i = 0; i < 16; i++) {
            int nn = rr + i * 4;
            w[(n0 + nn) * 256 + k0 + cc] = f_to_bfbits(tile[cc][nn]);
        }
    }
}

// ---------------- parallel scan (deg = real edges; dis = rsqrt(deg+1)) -----------
__global__ void k_scan1(const int* __restrict__ deg0, const int* __restrict__ deg1,
                        float* __restrict__ dis0, float* __restrict__ dis1,
                        int* __restrict__ bsum, int n) {
    int l = blockIdx.y;
    const int* deg = l ? deg1 : deg0;
    float* dis = l ? dis1 : dis0;
    int t = threadIdx.x;
    int base = blockIdx.x * 1024 + t * 4;
    int d[4] = {0, 0, 0, 0};
    if (base + 3 < n) {
        int4 q = *(const int4*)(deg + base);
        d[0] = q.x; d[1] = q.y; d[2] = q.z; d[3] = q.w;
    } else {
#pragma unroll
        for (int j = 0; j < 4; j++) if (base + j < n) d[j] = deg[base + j];
    }
#pragma unroll
    for (int j = 0; j < 4; j++)
        if (base + j < n) dis[base + j] = rsqrtf((float)(d[j] + 1));
    int s = d[0] + d[1] + d[2] + d[3];
#pragma unroll
    for (int off = 32; off >= 1; off >>= 1) s += __shfl_down(s, off, 64);
    __shared__ int ws[4];
    if ((t & 63) == 0) ws[t >> 6] = s;
    __syncthreads();
    if (t == 0) bsum[l * 64 + blockIdx.x] = ws[0] + ws[1] + ws[2] + ws[3];
}

__global__ void k_scan2(const int* __restrict__ bsum, int* __restrict__ boff) {
    int lane = threadIdx.x & 63;
    int l = threadIdx.x >> 6;
    int v = (lane < NB) ? bsum[l * 64 + lane] : 0;
    int s = v;
#pragma unroll
    for (int off = 1; off < 64; off <<= 1) {
        int u = __shfl_up(s, off, 64);
        if (lane >= off) s += u;
    }
    boff[l * 64 + lane] = s - v;   // exclusive
}

__global__ void k_scan3(const int* __restrict__ deg0, const int* __restrict__ deg1,
                        const int* __restrict__ boff,
                        int* __restrict__ cur0, int* __restrict__ cur1, int n) {
    int l = blockIdx.y;
    const int* deg = l ? deg1 : deg0;
    int* cur = l ? cur1 : cur0;
    int t = threadIdx.x;
    int base = blockIdx.x * 1024 + t * 4;
    int d[4] = {0, 0, 0, 0};
    if (base + 3 < n) {
        int4 q = *(const int4*)(deg + base);
        d[0] = q.x; d[1] = q.y; d[2] = q.z; d[3] = q.w;
    } else {
#pragma unroll
        for (int j = 0; j < 4; j++) if (base + j < n) d[j] = deg[base + j];
    }
    int s = d[0] + d[1] + d[2] + d[3];
    __shared__ int sc[256];
    sc[t] = s;
    __syncthreads();
    for (int off = 1; off < 256; off <<= 1) {
        int v = (t >= off) ? sc[t - off] : 0;
        __syncthreads();
        sc[t] += v;
        __syncthreads();
    }
    int p = boff[l * 64 + blockIdx.x] + sc[t] - s;   // exclusive prefix
#pragma unroll
    for (int j = 0; j < 4; j++) {
        if (base + j < n) { cur[base + j] = p; p += d[j]; }
    }
}

// ---- fill: 16B records {src, w1, w2, 0}, ATOMIC-FREE via precomputed ranks ----
// position = cur_start[col] + rank[i]; 4 edges/thread, vectorized loads.
__global__ __launch_bounds__(256)
void k_fill(const int* __restrict__ ei0, const void* __restrict__ ea0,
            const float* __restrict__ dis0, const int* __restrict__ cur0,
            const int* __restrict__ rank0, int4v* __restrict__ edges0,
            const int* __restrict__ ei1, const void* __restrict__ ea1,
            const float* __restrict__ dis1, const int* __restrict__ cur1,
            const int* __restrict__ rank1, int4v* __restrict__ edges1,
            const int* __restrict__ dflag) {
    int lvl = blockIdx.y;
    const int* row = lvl ? ei1 : ei0;
    const int* col = row + NE;
    const void* attr = lvl ? ea1 : ea0;
    const float* dis = lvl ? dis1 : dis0;
    const int* cur = lvl ? cur1 : cur0;
    const int* rank = lvl ? rank1 : rank0;
    int4v* edges = lvl ? edges1 : edges0;
    int i0 = (blockIdx.x * 256 + threadIdx.x) * 4;
    if (i0 >= NE) return;   // NE % 4 == 0 -> full quads only
    int4 rr = *(const int4*)(row + i0);
    int4 cc = *(const int4*)(col + i0);
    int4 rk = *(const int4*)(rank + i0);
    int isbf = dflag[0];
    float a[4];
    if (isbf) {
        unsigned short tmp[4];
        __builtin_memcpy(tmp, (const unsigned short*)attr + i0, 8);
#pragma unroll
        for (int j = 0; j < 4; j++) a[j] = bfbits_to_f(tmp[j]);
    } else {
        __builtin_memcpy(a, (const float*)attr + i0, 16);
    }
    int rv[4] = {rr.x, rr.y, rr.z, rr.w};
    int cv[4] = {cc.x, cc.y, cc.z, cc.w};
    int kv[4] = {rk.x, rk.y, rk.z, rk.w};
#pragma unroll
    for (int j = 0; j < 4; j++) {
        int p = cur[cv[j]] + kv[j];
        float w2 = (a[j] > 0.f) ? fminf(rsqrtf(a[j]), 1.f) : 0.f;
        int4v rec;
        rec.x = rv[j];
        rec.y = f_as_i(dis[rv[j]] * dis[cv[j]]);
        rec.z = f_as_i(w2);
        rec.w = 0;
        __builtin_nontemporal_store(rec, &edges[p]);
    }
}

// ---------------- GEMM core: 64x128 tile, K=256, bf16 MFMA ----------------
__device__ __forceinline__ void gemm_core(const unsigned short* __restrict__ A,
                                          const unsigned short* __restrict__ wt,
                                          int row0, float4v acc[8]) {
    __shared__ short A_s[64 * 72];
    __shared__ short B_s[128 * 72];
    int tid = threadIdx.x;
    int lane = tid & 63, w = tid >> 6;
    int m = lane & 15, quad = lane >> 4;
#pragma unroll
    for (int t = 0; t < 8; t++) acc[t] = (float4v){0.f, 0.f, 0.f, 0.f};
    for (int c = 0; c < 4; c++) {
#pragma unroll
        for (int i = 0; i < 2; i++) {
            int e = (i * 256 + tid) * 8;
            int r = e >> 6, cc = e & 63;
            int rr = row0 + r;
            short8 v = {0, 0, 0, 0, 0, 0, 0, 0};
            if (rr < NN) v = *(const short8*)(A + rr * 256 + c * 64 + cc);
            *(short8*)&A_s[r * 72 + cc] = v;
        }
#pragma unroll
        for (int i = 0; i < 4; i++) {
            int e = (i * 256 + tid) * 8;
            int nr = e >> 6, kk = e & 63;
            *(short8*)&B_s[nr * 72 + kk] = *(const short8*)(wt + nr * 256 + c * 64 + kk);
        }
        __syncthreads();
#pragma unroll
        for (int c2 = 0; c2 < 2; c2++) {
            short8 a = *(short8*)&A_s[(w * 16 + m) * 72 + c2 * 32 + quad * 8];
#pragma unroll
            for (int t = 0; t < 8; t++) {
                short8 b = *(short8*)&B_s[(t * 16 + m) * 72 + c2 * 32 + quad * 8];
                acc[t] = __builtin_amdgcn_mfma_f32_16x16x32_bf16(a, b, acc[t], 0, 0, 0);
            }
        }
        __syncthreads();
    }
}

// ---------------- PE GEMM: xpe{1,2} = xcat @ nodeLin{1,2} (plain write) ----------
__global__ __launch_bounds__(256)
void k_gemm_pe(const unsigned short* __restrict__ xcat,
               const unsigned short* __restrict__ wt,
               unsigned short* __restrict__ out0, unsigned short* __restrict__ out1) {
    float4v acc[8];
    gemm_core(xcat, wt + (blockIdx.y ? WSLOT : 0), blockIdx.x * 64, acc);
    unsigned short* out = blockIdx.y ? out1 : out0;
    int lane = threadIdx.x & 63, w = threadIdx.x >> 6;
    int m = lane & 15, quad = lane >> 4;
    int row0 = blockIdx.x * 64;
#pragma unroll
    for (int t = 0; t < 8; t++)
#pragma unroll
        for (int r = 0; r < 4; r++) {
            int row = row0 + w * 16 + quad * 4 + r;
            if (row < NN) out[row * DD + t * 16 + m] = f_to_bfbits(acc[t][r]);
        }
}

// ---------------- layer GEMM: out = epilogue(acat @ Wcat) ----------------
// mode 1: relu -> bf16 out
// mode 2: 0.5*relu + 0.5*blend -> bf16 out
// mode 3: 0.5*relu + 0.5*blend -> outFinal (bf16 or f32 per dflag)
__global__ __launch_bounds__(256)
void k_gemmL(const unsigned short* __restrict__ acat,
             const unsigned short* __restrict__ wt,
             const unsigned short* __restrict__ blendIn,
             unsigned short* __restrict__ out, void* __restrict__ outFinal,
             const int* __restrict__ dflag, int mode) {
    float4v acc[8];
    gemm_core(acat, wt, blockIdx.x * 64, acc);
    int lane = threadIdx.x & 63, w = threadIdx.x >> 6;
    int m = lane & 15, quad = lane >> 4;
    int row0 = blockIdx.x * 64;
    int isbf = (mode == 3) ? dflag[0] : 1;
#pragma unroll
    for (int t = 0; t < 8; t++) {
        int colc = t * 16 + m;
#pragma unroll
        for (int r = 0; r < 4; r++) {
            int row = row0 + w * 16 + quad * 4 + r;
            if (row >= NN) continue;
            float v = fmaxf(acc[t][r], 0.f);
            if (mode >= 2)
                v = 0.5f * v + 0.5f * bfbits_to_f(blendIn[row * DD + colc]);
            if (mode == 3 && !isbf)
                ((float*)outFinal)[row * DD + colc] = v;
            else if (mode == 3)
                ((unsigned short*)outFinal)[row * DD + colc] = f_to_bfbits(v);
            else
                out[row * DD + colc] = f_to_bfbits(v);
        }
    }
}

// ---------------- dual-level aggregation over X (a1|a2 -> acat[N,256]) ----------
// 2 waves per node, contiguous edge-list halves, LDS merge.
// lane = 2 cols; unroll-8; nontemporal record loads (don't thrash X in L2);
// analytic self-loop (w1 = dis^2, w2 = 1) applied by the merging wave.
// cur[] holds START offsets.
#define AEDGE(j) \
    int4v e##j = __builtin_nontemporal_load(&edges[s + j]); \
    unsigned int p##j = *(const unsigned int*)(X + e##j.x * DD + c0);
#define AACC(j, A1L, A1H, A2L, A2H) { \
    float w1_ = bits_to_f((unsigned int)e##j.y); \
    float w2_ = bits_to_f((unsigned int)e##j.z); \
    float xl_ = bits_to_f(p##j << 16); \
    float xh_ = bits_to_f(p##j & 0xFFFF0000u); \
    A1L = fmaf(w1_, xl_, A1L); A1H = fmaf(w1_, xh_, A1H); \
    A2L = fmaf(w2_, xl_, A2L); A2H = fmaf(w2_, xh_, A2H); }

__global__ __launch_bounds__(256)
void k_aggd(const int4v* __restrict__ edges0, const int* __restrict__ cur0,
            const int* __restrict__ deg0, const float* __restrict__ dis0,
            const unsigned short* __restrict__ X0, unsigned short* __restrict__ acat0,
            const int4v* __restrict__ edges1, const int* __restrict__ cur1,
            const int* __restrict__ deg1, const float* __restrict__ dis1,
            const unsigned short* __restrict__ X1, unsigned short* __restrict__ acat1) {
    __shared__ float red[2][2][128];   // [node-in-block][a1/a2][col]
    int b = blockIdx.x;
    int lvl = b >= AGG2B;
    const int4v* edges = lvl ? edges1 : edges0;
    const int* cur = lvl ? cur1 : cur0;
    const int* deg = lvl ? deg1 : deg0;
    const float* dis = lvl ? dis1 : dis0;
    const unsigned short* X = lvl ? X1 : X0;
    unsigned short* acat = lvl ? acat1 : acat0;
    int w = threadIdx.x >> 6;          // 0..3
    int lane = threadIdx.x & 63;
    int nib = w >> 1;                  // node in block (0/1)
    int half = w & 1;
    int node = (b - (lvl ? AGG2B : 0)) * 2 + nib;   // NN = 2*AGG2B exactly
    int start = cur[node];
    int d = deg[node];
    int h0 = d >> 1;
    int s = half ? (start + h0) : start;
    int e = half ? (start + d) : (start + h0);
    int c0 = lane * 2;
    float a1l0 = 0.f, a1h0 = 0.f, a2l0 = 0.f, a2h0 = 0.f;
    float a1l1 = 0.f, a1h1 = 0.f, a2l1 = 0.f, a2h1 = 0.f;
    for (; s + 8 <= e; s += 8) {
        AEDGE(0) AEDGE(1) AEDGE(2) AEDGE(3) AEDGE(4) AEDGE(5) AEDGE(6) AEDGE(7)
        AACC(0, a1l0, a1h0, a2l0, a2h0); AACC(1, a1l1, a1h1, a2l1, a2h1);
        AACC(2, a1l0, a1h0, a2l0, a2h0); AACC(3, a1l1, a1h1, a2l1, a2h1);
        AACC(4, a1l0, a1h0, a2l0, a2h0); AACC(5, a1l1, a1h1, a2l1, a2h1);
        AACC(6, a1l0, a1h0, a2l0, a2h0); AACC(7, a1l1, a1h1, a2l1, a2h1);
    }
    for (; s < e; s++) {
        AEDGE(0)
        AACC(0, a1l0, a1h0, a2l0, a2h0);
    }
    float s1l = a1l0 + a1l1, s1h = a1h0 + a1h1;
    float s2l = a2l0 + a2l1, s2h = a2h0 + a2h1;
    if (half == 1) {
        red[nib][0][c0]     = s1l;
        red[nib][0][c0 + 1] = s1h;
        red[nib][1][c0]     = s2l;
        red[nib][1][c0 + 1] = s2h;
    }
    __syncthreads();
    if (half == 0) {
        s1l += red[nib][0][c0];
        s1h += red[nib][0][c0 + 1];
        s2l += red[nib][1][c0];
        s2h += red[nib][1][c0 + 1];
        // analytic self loop
        float dn = dis[node];
        unsigned int q = *(const unsigned int*)(X + node * DD + c0);
        float xl = bits_to_f(q << 16), xh = bits_to_f(q & 0xFFFF0000u);
        float dn2 = dn * dn;
        s1l = fmaf(dn2, xl, s1l); s1h = fmaf(dn2, xh, s1h);
        s2l += xl; s2h += xh;
        unsigned int pk1 = (unsigned int)f_to_bfbits(s1l) |
                           ((unsigned int)f_to_bfbits(s1h) << 16);
        unsigned int pk2 = (unsigned int)f_to_bfbits(s2l) |
                           ((unsigned int)f_to_bfbits(s2h) << 16);
        __builtin_nontemporal_store(pk1, (unsigned int*)(acat + node * 256 + c0));
        __builtin_nontemporal_store(pk2, (unsigned int*)(acat + node * 256 + 128 + c0));
    }
}

// ---------------- Launch ----------------

#define PADUP(x) (((x) + 255) & ~(size_t)255)

extern "C" void kernel_launch(void* const* d_in, const int* in_sizes, int n_in,
                              void* d_out, int out_size, void* d_ws, size_t ws_size,
                              hipStream_t stream) {
    (void)in_sizes; (void)n_in; (void)out_size; (void)ws_size;

    const void* x    = d_in[0];
    const void* d2an = d_in[1];
    const int*  ei0  = (const int*)d_in[2];
    const void* ea0  = d_in[3];
    const int*  ei1  = (const int*)d_in[4];
    const void* ea1  = d_in[5];

    char* p = (char*)d_ws;
    unsigned short* xpe1 = (unsigned short*)p; p += PADUP((size_t)NN * DD * 2);
    unsigned short* xpe2 = (unsigned short*)p; p += PADUP((size_t)NN * DD * 2);
    unsigned short* x0b  = (unsigned short*)p; p += PADUP((size_t)NN * DD * 2);
    unsigned short* xm   = (unsigned short*)p; p += PADUP((size_t)NN * DD * 2);
    unsigned short* xcat = (unsigned short*)p; p += PADUP((size_t)NN * 256 * 2);
    unsigned short* acat0 = xcat;              // xcat dead after PE GEMM
    unsigned short* acat1 = (unsigned short*)p; p += PADUP((size_t)NN * 256 * 2);
    unsigned short* wt   = (unsigned short*)p; p += PADUP((size_t)6 * WSLOT * 2);
    int*   deg0 = (int*)p;    p += PADUP((size_t)NN * 4);
    int*   cur0 = (int*)p;    p += PADUP((size_t)NN * 4);
    float* dis0 = (float*)p;  p += PADUP((size_t)NN * 4);
    int*   deg1 = (int*)p;    p += PADUP((size_t)NN * 4);
    int*   cur1 = (int*)p;    p += PADUP((size_t)NN * 4);
    float* dis1 = (float*)p;  p += PADUP((size_t)NN * 4);
    int4v* edges0 = (int4v*)p; p += PADUP((size_t)NE * 16);
    int4v* edges1 = (int4v*)p; p += PADUP((size_t)NE * 16);
    int*   bsum = (int*)p;    p += PADUP((size_t)128 * 4);
    int*   boff = (int*)p;    p += PADUP((size_t)128 * 4);
    int*   dflag = (int*)p;

    // rank buffers alias xpe1/xpe2: written by kA, consumed by k_fill,
    // both strictly before k_gemm_pe writes xpe1/xpe2 (stream-ordered).
    int* rank0 = (int*)xpe1;   // NE*4 = 6.4MB <= NN*DD*2 = 12.8MB
    int* rank1 = (int*)xpe2;

    // 1. detect + zero degrees
    k_detect0<<<392, 256, 0, stream>>>((const unsigned int*)x, dflag, (float*)d_out,
                                       deg0, deg1);
    // 2. hist(+rank) + prepx + weight prep (fused streaming)
    kA<<<2 * HISTB + PREPXB + PREPB, 256, 0, stream>>>(
        ei0, ei1, deg0, deg1, rank0, rank1, x, d2an, xcat,
        d_in[6], d_in[7], d_in[8], d_in[9], d_in[10], d_in[11], d_in[12],
        d_in[13], d_in[14], d_in[15], wt, dflag);
    // 3-5. parallel scan
    k_scan1<<<dim3(NB, 2), 256, 0, stream>>>(deg0, deg1, dis0, dis1, bsum, NN);
    k_scan2<<<1, 128, 0, stream>>>(bsum, boff);
    k_scan3<<<dim3(NB, 2), 256, 0, stream>>>(deg0, deg1, boff, cur0, cur1, NN);
    // 6. edge fill — atomic-free via ranks
    k_fill<<<dim3(FILLB, 2), 256, 0, stream>>>(ei0, ea0, dis0, cur0, rank0, edges0,
                                               ei1, ea1, dis1, cur1, rank1, edges1,
                                               dflag);
    // 7. PE GEMM: xpe1/xpe2 = xcat @ nodeLin{1,2}   (overwrites rank buffers; ok)
    k_gemm_pe<<<dim3(GX, 2), 256, 0, stream>>>(xcat, wt, xpe1, xpe2);
    // 8. dual agg round 1: acat0 = agg0(xpe1), acat1 = agg1(xpe2)
    k_aggd<<<2 * AGG2B, 256, 0, stream>>>(edges0, cur0, deg0, dis0, xpe1, acat0,
                                          edges1, cur1, deg1, dis1, xpe2, acat1);
    // 9. x0 = relu(acat0 @ Wcat_1) -> x0b
    k_gemmL<<<GX, 256, 0, stream>>>(acat0, wt + 2 * WSLOT,
                                    (const unsigned short*)0, x0b, (void*)0,
                                    dflag, 1);
    // 10. xm = 0.5*relu(acat1 @ Wcat_2) + 0.5*x0b
    k_gemmL<<<GX, 256, 0, stream>>>(acat1, wt + 3 * WSLOT, x0b, xm, (void*)0,
                                    dflag, 2);
    // 11. dual agg round 2: acat0 = agg0(xm), acat1 = agg1(xm)
    k_aggd<<<2 * AGG2B, 256, 0, stream>>>(edges0, cur0, deg0, dis0, xm, acat0,
                                          edges1, cur1, deg1, dis1, xm, acat1);
    // 12. x0 = relu(acat0 @ Wcat_3) -> x0b
    k_gemmL<<<GX, 256, 0, stream>>>(acat0, wt + 4 * WSLOT,
                                    (const unsigned short*)0, x0b, (void*)0,
                                    dflag, 1);
    // 13. out = 0.5*relu(acat1 @ Wcat_4) + 0.5*x0b  (bf16/f32 per dflag)
    k_gemmL<<<GX, 256, 0, stream>>>(acat1, wt + 5 * WSLOT, x0b,
                                    (unsigned short*)0, d_out, dflag, 3);
}

// Round 6
// 491.148 us; speedup vs baseline: 1.4571x; 1.4571x over previous
//
#include <hip/hip_runtime.h>

#define NN 50000
#define NE 800000
#define DD 128
#define PEW 98
#define KPE 226
#define WSLOT 32768   // bf16 elements per weight slot (128 n x 256 k)
#define NB 49         // scan blocks per level: ceil(NN/1024)
#define GX 782        // ceil(NN/64) gemm row-tiles
#define HISTB 782     // ceil(NE/(256*4)) hist blocks per level (4 edges/thread)
#define FILLB 782     // ceil(NE/(256*4)) fill blocks per level
#define PREPXB 6250   // NN*256/(256*8) prepx blocks (8 elems/thread)
#define PREPB 48      // 6 slots x 8 tile-blocks
#define AGGB 12500    // ceil(NN/4): 1 wave per node, 4 nodes/block

typedef __attribute__((ext_vector_type(8))) short short8;
typedef __attribute__((ext_vector_type(4))) float float4v;

// Kept so anything that looks up the original kernel name still finds a symbol.
__global__ void GraphTrajSTEncoder_67362267070834_kernel() {}

// ---------------- dtype helpers ----------------

__device__ __forceinline__ float bfbits_to_f(unsigned int u16) {
    unsigned int v = u16 << 16;
    float f;
    __builtin_memcpy(&f, &v, 4);
    return f;
}

__device__ __forceinline__ float bits_to_f(unsigned int v) {
    float f;
    __builtin_memcpy(&f, &v, 4);
    return f;
}

__device__ __forceinline__ int f_as_i(float f) {
    int i;
    __builtin_memcpy(&i, &f, 4);
    return i;
}

__device__ __forceinline__ unsigned short f_to_bfbits(float f) {
    unsigned int b;
    __builtin_memcpy(&b, &f, 4);
    unsigned int r = b + 0x7FFFu + ((b >> 16) & 1u);   // round to nearest even
    return (unsigned short)(r >> 16);
}

__device__ __forceinline__ float ldf(const void* p, int i, int isbf) {
    if (isbf) return bfbits_to_f(((const unsigned short*)p)[i]);
    return ((const float*)p)[i];
}

// ---------------- dispatch 1: dtype detect + zero degree arrays ----------------
__global__ __launch_bounds__(256)
void k_detect0(const unsigned int* xw, int* flag, float* dout_sentinel,
               int* deg0, int* deg1) {
    if (blockIdx.x == 0) {
        __shared__ int cnt;
        if (threadIdx.x == 0) cnt = 0;
        __syncthreads();
        unsigned int w = xw[threadIdx.x];
        unsigned int e = (w >> 7) & 0xFFu;
        atomicAdd(&cnt, (e >= 100u && e <= 150u) ? 1 : 0);
        __syncthreads();
        if (threadIdx.x == 0) {
            flag[0] = (cnt >= 128) ? 1 : 0;
            dout_sentinel[0] = 1.0e6f;
        }
    } else {
        int i = (blockIdx.x - 1) * 256 + threadIdx.x;
        if (i < NN) deg0[i] = 0;
        else if (i < 2 * NN) deg1[i - NN] = 0;
    }
}

// ---------------- dispatch 2 (kA): hist(+rank) + prepx + weight-prep -------
// hist: 4 edges/thread, atomicAdd returns per-edge rank within node -> rank_buf
// prepx: 8 elems/thread, vectorized
// slot y (0..5), Wt[n*256 + k]:
//   y<2 : nodeLin y   -> src[k*128+n], k<226, else 0
//   y>=2: layer y-2   -> k<128: lin1[k*128+n]; k>=128: lin2[(k-128)*128+n]
__global__ __launch_bounds__(256)
void kA(const int* __restrict__ ei0, const int* __restrict__ ei1,
        int* deg0, int* deg1,
        int* __restrict__ rank0, int* __restrict__ rank1,
        const void* x, const void* pe, unsigned short* __restrict__ xcat,
        const void* n1, const void* n2,
        const void* l11, const void* l21, const void* l12, const void* l22,
        const void* l13, const void* l23, const void* l14, const void* l24,
        unsigned short* __restrict__ wt, const int* __restrict__ dflag) {
    int b = blockIdx.x;
    int t = threadIdx.x;
    if (b < 2 * HISTB) {
        int lvl = b >= HISTB;
        const int* col = (lvl ? ei1 : ei0) + NE;
        int* deg = lvl ? deg1 : deg0;
        int* rank = lvl ? rank1 : rank0;
        int i0 = ((b - (lvl ? HISTB : 0)) * 256 + t) * 4;
        if (i0 < NE) {   // NE % 4 == 0 -> full quads only
            int4 c = *(const int4*)(col + i0);
            int4 r;
            r.x = atomicAdd(&deg[c.x], 1);
            r.y = atomicAdd(&deg[c.y], 1);
            r.z = atomicAdd(&deg[c.z], 1);
            r.w = atomicAdd(&deg[c.w], 1);
            *(int4*)(rank + i0) = r;
        }
    } else if (b < 2 * HISTB + PREPXB) {
        int isbf = dflag[0];
        int id0 = (b - 2 * HISTB) * 2048 + t * 8;
        int row = id0 >> 8, c0 = id0 & 255;   // c0 is a multiple of 8
        union { unsigned short u[8]; short8 v; } ob;
        if (c0 < DD) {
            // 8 consecutive x columns
            if (isbf) {
                ob.v = *(const short8*)((const unsigned short*)x + row * DD + c0);
            } else {
                float f[8];
                __builtin_memcpy(f, (const float*)x + row * DD + c0, 32);
#pragma unroll
                for (int j = 0; j < 8; j++) ob.u[j] = f_to_bfbits(f[j]);
            }
        } else if (c0 + 8 <= KPE) {
            // 8 consecutive pe columns (c0 = 128..216)
            int off = row * PEW + (c0 - DD);
            if (isbf) {
                unsigned short tmp[8];
                __builtin_memcpy(tmp, (const unsigned short*)pe + off, 16);
#pragma unroll
                for (int j = 0; j < 8; j++) ob.u[j] = tmp[j];
            } else {
                float f[8];
                __builtin_memcpy(f, (const float*)pe + off, 32);
#pragma unroll
                for (int j = 0; j < 8; j++) ob.u[j] = f_to_bfbits(f[j]);
            }
        } else {
            // mixed tail (c0 = 224) or pure zero pad (c0 = 232/240/248)
#pragma unroll
            for (int j = 0; j < 8; j++) {
                int c = c0 + j;
                float v = 0.f;
                if (c < KPE) v = ldf(pe, row * PEW + (c - DD), isbf);
                ob.u[j] = f_to_bfbits(v);
            }
        }
        *(short8*)(xcat + id0) = ob.v;
    } else {
        int b3 = b - 2 * HISTB - PREPXB;
        int y = b3 >> 3, bx = b3 & 7;
        int kt = bx >> 1, nt = bx & 1;
        __shared__ float tile[64][65];
        int cc = t & 63, rr = t >> 6;
        int k0 = kt * 64, n0 = nt * 64;
        int isbf = dflag[0];
        const void* sA;   // source for k<128
        const void* sB;   // source for k>=128
        if (y == 0)      { sA = n1;  sB = n1; }
        else if (y == 1) { sA = n2;  sB = n2; }
        else if (y == 2) { sA = l11; sB = l21; }
        else if (y == 3) { sA = l12; sB = l22; }
        else if (y == 4) { sA = l13; sB = l23; }
        else             { sA = l14; sB = l24; }
#pragma unroll
        for (int i = 0; i < 16; i++) {
            int k = k0 + rr + i * 4;
            float v = 0.f;
            if (y < 2) {
                if (k < KPE) v = ldf(sA, k * DD + n0 + cc, isbf);
            } else {
                v = (k < 128) ? ldf(sA, k * DD + n0 + cc, isbf)
                              : ldf(sB, (k - 128) * DD + n0 + cc, isbf);
            }
            tile[rr + i * 4][cc] = v;
        }
        __syncthreads();
        unsigned short* w = wt + y * WSLOT;
#pragma unroll
        for (int i = 0; i < 16; i++) {
            int nn = rr + i * 4;
            w[(n0 + nn) * 256 + k0 + cc] = f_to_bfbits(tile[cc][nn]);
        }
    }
}

// ---------------- parallel scan (deg = real edges; dis = rsqrt(deg+1)) -----------
__global__ void k_scan1(const int* __restrict__ deg0, const int* __restrict__ deg1,
                        float* __restrict__ dis0, float* __restrict__ dis1,
                        int* __restrict__ bsum, int n) {
    int l = blockIdx.y;
    const int* deg = l ? deg1 : deg0;
    float* dis = l ? dis1 : dis0;
    int t = threadIdx.x;
    int base = blockIdx.x * 1024 + t * 4;
    int d[4] = {0, 0, 0, 0};
    if (base + 3 < n) {
        int4 q = *(const int4*)(deg + base);
        d[0] = q.x; d[1] = q.y; d[2] = q.z; d[3] = q.w;
    } else {
#pragma unroll
        for (int j = 0; j < 4; j++) if (base + j < n) d[j] = deg[base + j];
    }
#pragma unroll
    for (int j = 0; j < 4; j++)
        if (base + j < n) dis[base + j] = rsqrtf((float)(d[j] + 1));
    int s = d[0] + d[1] + d[2] + d[3];
#pragma unroll
    for (int off = 32; off >= 1; off >>= 1) s += __shfl_down(s, off, 64);
    __shared__ int ws[4];
    if ((t & 63) == 0) ws[t >> 6] = s;
    __syncthreads();
    if (t == 0) bsum[l * 64 + blockIdx.x] = ws[0] + ws[1] + ws[2] + ws[3];
}

__global__ void k_scan2(const int* __restrict__ bsum, int* __restrict__ boff) {
    int lane = threadIdx.x & 63;
    int l = threadIdx.x >> 6;
    int v = (lane < NB) ? bsum[l * 64 + lane] : 0;
    int s = v;
#pragma unroll
    for (int off = 1; off < 64; off <<= 1) {
        int u = __shfl_up(s, off, 64);
        if (lane >= off) s += u;
    }
    boff[l * 64 + lane] = s - v;   // exclusive
}

__global__ void k_scan3(const int* __restrict__ deg0, const int* __restrict__ deg1,
                        const int* __restrict__ boff,
                        int* __restrict__ cur0, int* __restrict__ cur1, int n) {
    int l = blockIdx.y;
    const int* deg = l ? deg1 : deg0;
    int* cur = l ? cur1 : cur0;
    int t = threadIdx.x;
    int base = blockIdx.x * 1024 + t * 4;
    int d[4] = {0, 0, 0, 0};
    if (base + 3 < n) {
        int4 q = *(const int4*)(deg + base);
        d[0] = q.x; d[1] = q.y; d[2] = q.z; d[3] = q.w;
    } else {
#pragma unroll
        for (int j = 0; j < 4; j++) if (base + j < n) d[j] = deg[base + j];
    }
    int s = d[0] + d[1] + d[2] + d[3];
    __shared__ int sc[256];
    sc[t] = s;
    __syncthreads();
    for (int off = 1; off < 256; off <<= 1) {
        int v = (t >= off) ? sc[t - off] : 0;
        __syncthreads();
        sc[t] += v;
        __syncthreads();
    }
    int p = boff[l * 64 + blockIdx.x] + sc[t] - s;   // exclusive prefix
#pragma unroll
    for (int j = 0; j < 4; j++) {
        if (base + j < n) { cur[base + j] = p; p += d[j]; }
    }
}

// ---- fill: 16B records {src, w1, w2, 0}, ATOMIC-FREE via precomputed ranks ----
// position = cur_start[col] + rank[i]; 4 edges/thread, vectorized loads.
// Plain stores (records must stay L2-resident for k_aggd's tile reads).
__global__ __launch_bounds__(256)
void k_fill(const int* __restrict__ ei0, const void* __restrict__ ea0,
            const float* __restrict__ dis0, const int* __restrict__ cur0,
            const int* __restrict__ rank0, int4* __restrict__ edges0,
            const int* __restrict__ ei1, const void* __restrict__ ea1,
            const float* __restrict__ dis1, const int* __restrict__ cur1,
            const int* __restrict__ rank1, int4* __restrict__ edges1,
            const int* __restrict__ dflag) {
    int lvl = blockIdx.y;
    const int* row = lvl ? ei1 : ei0;
    const int* col = row + NE;
    const void* attr = lvl ? ea1 : ea0;
    const float* dis = lvl ? dis1 : dis0;
    const int* cur = lvl ? cur1 : cur0;
    const int* rank = lvl ? rank1 : rank0;
    int4* edges = lvl ? edges1 : edges0;
    int i0 = (blockIdx.x * 256 + threadIdx.x) * 4;
    if (i0 >= NE) return;   // NE % 4 == 0 -> full quads only
    int4 rr = *(const int4*)(row + i0);
    int4 cc = *(const int4*)(col + i0);
    int4 rk = *(const int4*)(rank + i0);
    int isbf = dflag[0];
    float a[4];
    if (isbf) {
        unsigned short tmp[4];
        __builtin_memcpy(tmp, (const unsigned short*)attr + i0, 8);
#pragma unroll
        for (int j = 0; j < 4; j++) a[j] = bfbits_to_f(tmp[j]);
    } else {
        __builtin_memcpy(a, (const float*)attr + i0, 16);
    }
    int rv[4] = {rr.x, rr.y, rr.z, rr.w};
    int cv[4] = {cc.x, cc.y, cc.z, cc.w};
    int kv[4] = {rk.x, rk.y, rk.z, rk.w};
#pragma unroll
    for (int j = 0; j < 4; j++) {
        int p = cur[cv[j]] + kv[j];
        float w2 = (a[j] > 0.f) ? fminf(rsqrtf(a[j]), 1.f) : 0.f;
        int4 rec;
        rec.x = rv[j];
        rec.y = f_as_i(dis[rv[j]] * dis[cv[j]]);
        rec.z = f_as_i(w2);
        rec.w = 0;
        edges[p] = rec;
    }
}

// ---------------- GEMM core: 64x128 tile, K=256, bf16 MFMA ----------------
__device__ __forceinline__ void gemm_core(const unsigned short* __restrict__ A,
                                          const unsigned short* __restrict__ wt,
                                          int row0, float4v acc[8]) {
    __shared__ short A_s[64 * 72];
    __shared__ short B_s[128 * 72];
    int tid = threadIdx.x;
    int lane = tid & 63, w = tid >> 6;
    int m = lane & 15, quad = lane >> 4;
#pragma unroll
    for (int t = 0; t < 8; t++) acc[t] = (float4v){0.f, 0.f, 0.f, 0.f};
    for (int c = 0; c < 4; c++) {
#pragma unroll
        for (int i = 0; i < 2; i++) {
            int e = (i * 256 + tid) * 8;
            int r = e >> 6, cc = e & 63;
            int rr = row0 + r;
            short8 v = {0, 0, 0, 0, 0, 0, 0, 0};
            if (rr < NN) v = *(const short8*)(A + rr * 256 + c * 64 + cc);
            *(short8*)&A_s[r * 72 + cc] = v;
        }
#pragma unroll
        for (int i = 0; i < 4; i++) {
            int e = (i * 256 + tid) * 8;
            int nr = e >> 6, kk = e & 63;
            *(short8*)&B_s[nr * 72 + kk] = *(const short8*)(wt + nr * 256 + c * 64 + kk);
        }
        __syncthreads();
#pragma unroll
        for (int c2 = 0; c2 < 2; c2++) {
            short8 a = *(short8*)&A_s[(w * 16 + m) * 72 + c2 * 32 + quad * 8];
#pragma unroll
            for (int t = 0; t < 8; t++) {
                short8 b = *(short8*)&B_s[(t * 16 + m) * 72 + c2 * 32 + quad * 8];
                acc[t] = __builtin_amdgcn_mfma_f32_16x16x32_bf16(a, b, acc[t], 0, 0, 0);
            }
        }
        __syncthreads();
    }
}

// ---------------- PE GEMM: xpe{1,2} = xcat @ nodeLin{1,2} (plain write) ----------
__global__ __launch_bounds__(256)
void k_gemm_pe(const unsigned short* __restrict__ xcat,
               const unsigned short* __restrict__ wt,
               unsigned short* __restrict__ out0, unsigned short* __restrict__ out1) {
    float4v acc[8];
    gemm_core(xcat, wt + (blockIdx.y ? WSLOT : 0), blockIdx.x * 64, acc);
    unsigned short* out = blockIdx.y ? out1 : out0;
    int lane = threadIdx.x & 63, w = threadIdx.x >> 6;
    int m = lane & 15, quad = lane >> 4;
    int row0 = blockIdx.x * 64;
#pragma unroll
    for (int t = 0; t < 8; t++)
#pragma unroll
        for (int r = 0; r < 4; r++) {
            int row = row0 + w * 16 + quad * 4 + r;
            if (row < NN) out[row * DD + t * 16 + m] = f_to_bfbits(acc[t][r]);
        }
}

// ---------------- layer GEMM: out = epilogue(acat @ Wcat) ----------------
// mode 1: relu -> bf16 out
// mode 2: 0.5*relu + 0.5*blend -> bf16 out
// mode 3: 0.5*relu + 0.5*blend -> outFinal (bf16 or f32 per dflag)
__global__ __launch_bounds__(256)
void k_gemmL(const unsigned short* __restrict__ acat,
             const unsigned short* __restrict__ wt,
             const unsigned short* __restrict__ blendIn,
             unsigned short* __restrict__ out, void* __restrict__ outFinal,
             const int* __restrict__ dflag, int mode) {
    float4v acc[8];
    gemm_core(acat, wt, blockIdx.x * 64, acc);
    int lane = threadIdx.x & 63, w = threadIdx.x >> 6;
    int m = lane & 15, quad = lane >> 4;
    int row0 = blockIdx.x * 64;
    int isbf = (mode == 3) ? dflag[0] : 1;
#pragma unroll
    for (int t = 0; t < 8; t++) {
        int colc = t * 16 + m;
#pragma unroll
        for (int r = 0; r < 4; r++) {
            int row = row0 + w * 16 + quad * 4 + r;
            if (row >= NN) continue;
            float v = fmaxf(acc[t][r], 0.f);
            if (mode >= 2)
                v = 0.5f * v + 0.5f * bfbits_to_f(blendIn[row * DD + colc]);
            if (mode == 3 && !isbf)
                ((float*)outFinal)[row * DD + colc] = v;
            else if (mode == 3)
                ((unsigned short*)outFinal)[row * DD + colc] = f_to_bfbits(v);
            else
                out[row * DD + colc] = f_to_bfbits(v);
        }
    }
}

// ---------------- dual-level aggregation over X (a1|a2 -> acat[N,256]) ----------
// 1 wave per node. LANE-TILED record read: lane i loads record (start+i)
// (one coalesced 1KB load covers up to 64 edges), then each edge's
// {src,w1,w2} is broadcast via __shfl — no per-edge record memory latency,
// no serial tail (OOB edges get zeroed weights, gathers clamped to a valid
// row). Gathers issued 8-at-a-time for MLP. Analytic self-loop.
// cur[] holds START offsets.
__global__ __launch_bounds__(256)
void k_aggd(const int4* __restrict__ edges0, const int* __restrict__ cur0,
            const int* __restrict__ deg0, const float* __restrict__ dis0,
            const unsigned short* __restrict__ X0, unsigned short* __restrict__ acat0,
            const int4* __restrict__ edges1, const int* __restrict__ cur1,
            const int* __restrict__ deg1, const float* __restrict__ dis1,
            const unsigned short* __restrict__ X1, unsigned short* __restrict__ acat1) {
    int b = blockIdx.x;
    int lvl = b >= AGGB;
    const int4* edges = lvl ? edges1 : edges0;
    const int* cur = lvl ? cur1 : cur0;
    const int* deg = lvl ? deg1 : deg0;
    const float* dis = lvl ? dis1 : dis0;
    const unsigned short* X = lvl ? X1 : X0;
    unsigned short* acat = lvl ? acat1 : acat0;
    int wave = ((b - (lvl ? AGGB : 0)) * 256 + threadIdx.x) >> 6;
    int lane = threadIdx.x & 63;
    if (wave >= NN) return;
    int start = cur[wave];
    int d = deg[wave];
    int end = start + d;
    float dn = dis[wave];
    int c0 = lane * 2;
    float a1l0 = 0.f, a1h0 = 0.f, a2l0 = 0.f, a2h0 = 0.f;
    float a1l1 = 0.f, a1h1 = 0.f, a2l1 = 0.f, a2h1 = 0.f;
    int s = start;
    while (s < end) {
        int take = end - s;
        if (take > 64) take = 64;
        int li = s + lane;
        int4 rec = edges[(li < end) ? li : (end - 1)];
        for (int j0 = 0; j0 < take; j0 += 8) {
            int   src[8];
            float w1[8], w2[8];
#pragma unroll
            for (int jj = 0; jj < 8; jj++) {
                int j = j0 + jj;
                src[jj] = __shfl(rec.x, j, 64);
                float ww1 = bits_to_f((unsigned int)__shfl(rec.y, j, 64));
                float ww2 = bits_to_f((unsigned int)__shfl(rec.z, j, 64));
                int ok = j < take;
                w1[jj] = ok ? ww1 : 0.f;
                w2[jj] = ok ? ww2 : 0.f;
            }
            unsigned int q[8];
#pragma unroll
            for (int jj = 0; jj < 8; jj++)
                q[jj] = *(const unsigned int*)(X + src[jj] * DD + c0);
#pragma unroll
            for (int jj = 0; jj < 8; jj++) {
                float xl = bits_to_f(q[jj] << 16);
                float xh = bits_to_f(q[jj] & 0xFFFF0000u);
                if (jj & 1) {
                    a1l1 = fmaf(w1[jj], xl, a1l1); a1h1 = fmaf(w1[jj], xh, a1h1);
                    a2l1 = fmaf(w2[jj], xl, a2l1); a2h1 = fmaf(w2[jj], xh, a2h1);
                } else {
                    a1l0 = fmaf(w1[jj], xl, a1l0); a1h0 = fmaf(w1[jj], xh, a1h0);
                    a2l0 = fmaf(w2[jj], xl, a2l0); a2h0 = fmaf(w2[jj], xh, a2h0);
                }
            }
        }
        s += take;
    }
    // analytic self loop
    {
        unsigned int q = *(const unsigned int*)(X + wave * DD + c0);
        float xl = bits_to_f(q << 16), xh = bits_to_f(q & 0xFFFF0000u);
        float dn2 = dn * dn;
        a1l0 = fmaf(dn2, xl, a1l0); a1h0 = fmaf(dn2, xh, a1h0);
        a2l0 += xl; a2h0 += xh;
    }
    float s1l = a1l0 + a1l1, s1h = a1h0 + a1h1;
    float s2l = a2l0 + a2l1, s2h = a2h0 + a2h1;
    unsigned int pk1 = (unsigned int)f_to_bfbits(s1l) |
                       ((unsigned int)f_to_bfbits(s1h) << 16);
    unsigned int pk2 = (unsigned int)f_to_bfbits(s2l) |
                       ((unsigned int)f_to_bfbits(s2h) << 16);
    *(unsigned int*)(acat + wave * 256 + c0) = pk1;
    *(unsigned int*)(acat + wave * 256 + 128 + c0) = pk2;
}

// ---------------- Launch ----------------

#define PADUP(x) (((x) + 255) & ~(size_t)255)

extern "C" void kernel_launch(void* const* d_in, const int* in_sizes, int n_in,
                              void* d_out, int out_size, void* d_ws, size_t ws_size,
                              hipStream_t stream) {
    (void)in_sizes; (void)n_in; (void)out_size; (void)ws_size;

    const void* x    = d_in[0];
    const void* d2an = d_in[1];
    const int*  ei0  = (const int*)d_in[2];
    const void* ea0  = d_in[3];
    const int*  ei1  = (const int*)d_in[4];
    const void* ea1  = d_in[5];

    char* p = (char*)d_ws;
    unsigned short* xpe1 = (unsigned short*)p; p += PADUP((size_t)NN * DD * 2);
    unsigned short* xpe2 = (unsigned short*)p; p += PADUP((size_t)NN * DD * 2);
    unsigned short* x0b  = (unsigned short*)p; p += PADUP((size_t)NN * DD * 2);
    unsigned short* xm   = (unsigned short*)p; p += PADUP((size_t)NN * DD * 2);
    unsigned short* xcat = (unsigned short*)p; p += PADUP((size_t)NN * 256 * 2);
    unsigned short* acat0 = xcat;              // xcat dead after PE GEMM
    unsigned short* acat1 = (unsigned short*)p; p += PADUP((size_t)NN * 256 * 2);
    unsigned short* wt   = (unsigned short*)p; p += PADUP((size_t)6 * WSLOT * 2);
    int*   deg0 = (int*)p;    p += PADUP((size_t)NN * 4);
    int*   cur0 = (int*)p;    p += PADUP((size_t)NN * 4);
    float* dis0 = (float*)p;  p += PADUP((size_t)NN * 4);
    int*   deg1 = (int*)p;    p += PADUP((size_t)NN * 4);
    int*   cur1 = (int*)p;    p += PADUP((size_t)NN * 4);
    float* dis1 = (float*)p;  p += PADUP((size_t)NN * 4);
    int4*  edges0 = (int4*)p; p += PADUP((size_t)NE * 16);
    int4*  edges1 = (int4*)p; p += PADUP((size_t)NE * 16);
    int*   bsum = (int*)p;    p += PADUP((size_t)128 * 4);
    int*   boff = (int*)p;    p += PADUP((size_t)128 * 4);
    int*   dflag = (int*)p;

    // rank buffers alias xpe1/xpe2: written by kA, consumed by k_fill,
    // both strictly before k_gemm_pe writes xpe1/xpe2 (stream-ordered).
    int* rank0 = (int*)xpe1;   // NE*4 = 6.4MB <= NN*DD*2 = 12.8MB
    int* rank1 = (int*)xpe2;

    // 1. detect + zero degrees
    k_detect0<<<392, 256, 0, stream>>>((const unsigned int*)x, dflag, (float*)d_out,
                                       deg0, deg1);
    // 2. hist(+rank) + prepx + weight prep (fused streaming)
    kA<<<2 * HISTB + PREPXB + PREPB, 256, 0, stream>>>(
        ei0, ei1, deg0, deg1, rank0, rank1, x, d2an, xcat,
        d_in[6], d_in[7], d_in[8], d_in[9], d_in[10], d_in[11], d_in[12],
        d_in[13], d_in[14], d_in[15], wt, dflag);
    // 3-5. parallel scan
    k_scan1<<<dim3(NB, 2), 256, 0, stream>>>(deg0, deg1, dis0, dis1, bsum, NN);
    k_scan2<<<1, 128, 0, stream>>>(bsum, boff);
    k_scan3<<<dim3(NB, 2), 256, 0, stream>>>(deg0, deg1, boff, cur0, cur1, NN);
    // 6. edge fill — atomic-free via ranks
    k_fill<<<dim3(FILLB, 2), 256, 0, stream>>>(ei0, ea0, dis0, cur0, rank0, edges0,
                                               ei1, ea1, dis1, cur1, rank1, edges1,
                                               dflag);
    // 7. PE GEMM: xpe1/xpe2 = xcat @ nodeLin{1,2}   (overwrites rank buffers; ok)
    k_gemm_pe<<<dim3(GX, 2), 256, 0, stream>>>(xcat, wt, xpe1, xpe2);
    // 8. dual agg round 1: acat0 = agg0(xpe1), acat1 = agg1(xpe2)
    k_aggd<<<2 * AGGB, 256, 0, stream>>>(edges0, cur0, deg0, dis0, xpe1, acat0,
                                         edges1, cur1, deg1, dis1, xpe2, acat1);
    // 9. x0 = relu(acat0 @ Wcat_1) -> x0b
    k_gemmL<<<GX, 256, 0, stream>>>(acat0, wt + 2 * WSLOT,
                                    (const unsigned short*)0, x0b, (void*)0,
                                    dflag, 1);
    // 10. xm = 0.5*relu(acat1 @ Wcat_2) + 0.5*x0b
    k_gemmL<<<GX, 256, 0, stream>>>(acat1, wt + 3 * WSLOT, x0b, xm, (void*)0,
                                    dflag, 2);
    // 11. dual agg round 2: acat0 = agg0(xm), acat1 = agg1(xm)
    k_aggd<<<2 * AGGB, 256, 0, stream>>>(edges0, cur0, deg0, dis0, xm, acat0,
                                         edges1, cur1, deg1, dis1, xm, acat1);
    // 12. x0 = relu(acat0 @ Wcat_3) -> x0b
    k_gemmL<<<GX, 256, 0, stream>>>(acat0, wt + 4 * WSLOT,
                                    (const unsigned short*)0, x0b, (void*)0,
                                    dflag, 1);
    // 13. out = 0.5*relu(acat1 @ Wcat_4) + 0.5*x0b  (bf16/f32 per dflag)
    k_gemmL<<<GX, 256, 0, stream>>>(acat1, wt + 5 * WSLOT, x0b,
                                    (unsigned short*)0, d_out, dflag, 3);
}